// Round 15
// baseline (1152.131 us; speedup 1.0000x reference)
//
#include <hip/hip_runtime.h>
#include <stdint.h>

#define B_  64
#define T_  512
#define I_  512
#define H_  1024
#define G4  4096
#define KW  1536   // rows of W_t = I_ + H_

#define GROUPS 4
#define GBLK   64    // col-blocks per group
#define MBR    16    // batch rows per group

#define LDS_BYTES 66048

typedef __attribute__((ext_vector_type(8))) short bf16x8;
typedef __attribute__((ext_vector_type(4))) float f32x4;

// ---- ws layout (bytes) ----
#define OFF_WT   ((size_t)0)                        // 4096*1536*2 = 12,582,912
#define OFF_XB   ((size_t)(16u << 20))              // x bf16: 64*512*512*2 = 33,554,432
#define OFF_HB   (OFF_XB + (size_t)33554432)        // tagged h: 2 par * 4 grp * 16 * 1024 * 2B = 262,144
#define WS_NEED  (OFF_HB + (size_t)262144)

__device__ __forceinline__ unsigned short f2bf(float x) {
  unsigned u = __float_as_uint(x);
  u += 0x7FFFu + ((u >> 16) & 1u);        // RNE
  return (unsigned short)(u >> 16);
}
__device__ __forceinline__ float sigm(float x) {
  return 1.0f / (1.0f + __expf(-x));
}
__device__ __forceinline__ float fast_tanh(float x) {
  const float e2 = __expf(2.0f * x);
  return 1.0f - 2.0f / (e2 + 1.0f);
}

// ============ kernel 0: pack [U;V] -> W_t[col][k] bf16 (transposed) ============
__global__ __launch_bounds__(256) void pack_w_kernel(
    const float* __restrict__ U0, const float* __restrict__ U1,
    const float* __restrict__ U2, const float* __restrict__ U3,
    const float* __restrict__ V0, const float* __restrict__ V1,
    const float* __restrict__ V2, const float* __restrict__ V3,
    short* __restrict__ Wt)
{
  __shared__ short sl[64][65];
  const int c0 = blockIdx.x * 64;
  const int k0 = blockIdx.y * 64;
  const int g  = c0 >> 10;
  const int h0 = c0 & 1023;
  const float* srcU = (g == 0 ? U0 : g == 1 ? U1 : g == 2 ? U2 : U3);
  const float* srcV = (g == 0 ? V0 : g == 1 ? V1 : g == 2 ? V2 : V3);
  const float* src  = (k0 < 512) ? (srcU + (size_t)k0 * H_)
                                 : (srcV + (size_t)(k0 - 512) * H_);
  const int tid = threadIdx.x;
  const int cl = tid & 63;
  const int r4 = tid >> 6;
  #pragma unroll
  for (int r = 0; r < 16; ++r) {
    const int kl = r * 4 + r4;
    sl[kl][cl] = (short)f2bf(src[(size_t)kl * H_ + h0 + cl]);
  }
  __syncthreads();
  #pragma unroll
  for (int r = 0; r < 16; ++r) {
    const int cl2 = r * 4 + r4;
    Wt[(size_t)(c0 + cl2) * KW + k0 + cl] = sl[cl][cl2];
  }
}

// ============ kernel 1: x fp32 -> bf16 ============
__global__ __launch_bounds__(256) void xcvt(
    const float* __restrict__ x, short* __restrict__ xb)
{
  const int nt = 524288;
  const int idx = blockIdx.x * 256 + threadIdx.x;
  #pragma unroll
  for (int i = 0; i < 8; ++i) {
    const int j = idx + i * nt;
    const float4 v = ((const float4*)x)[j];
    uint2 pk;
    pk.x = (unsigned)f2bf(v.x) | ((unsigned)f2bf(v.y) << 16);
    pk.y = (unsigned)f2bf(v.z) | ((unsigned)f2bf(v.w) << 16);
    ((uint2*)xb)[j] = pk;
  }
}

// fragment address (shorts): slot XOR-swizzled within unit
#define FR_ADDR(unit, slot) ((((unit) * 64) + ((slot) ^ ((unit) & 7))) * 8)

// ============ kernel 2: persistent recurrence; V in regs; tag-in-data sync ============
__global__ __launch_bounds__(512, 2) void lstm_rec(
    const short* __restrict__ Wt, const short* __restrict__ xb,
    const float* __restrict__ b0g, const float* __restrict__ b1g,
    const float* __restrict__ b2g, const float* __restrict__ b3g,
    short* __restrict__ hb, float* __restrict__ out)
{
  extern __shared__ char smem[];
  short* sh = (short*)smem;                 // 32 KiB h frags (32 units x 64 slots x 16B)
  short* sx = (short*)(smem + 32768);       // 16 KiB x frags (16 units)
  float* gl = (float*)(smem + 49152);       // [16 rows][260] f32 partial-gate exchange

  const int tid = threadIdx.x;
  const int blk = blockIdx.x;
  const int g   = blk >> 6;                 // group (16 batch rows)
  const int bi  = blk & 63;
  const int base = bi * 16;                 // 16 h-cols per block per gate
  const int b0  = g * MBR;

  const int w = tid >> 6, l = tid & 63;
  const int kq = w & 3;                     // K quarter (256 of V-K, 128 of x-K)
  const int np = w >> 2;                    // col half: gates {2np, 2np+1}
  const int cit = l & 15;
  const int l16 = l >> 4;
  const int slot_r = (cit << 2) | l16;

  // ---- one-time: V fragments -> 64 VGPRs, U fragments -> 32 VGPRs ----
  bf16x8 vfr[2][8];
  bf16x8 ufr[2][4];
  #pragma unroll
  for (int n = 0; n < 2; ++n) {
    const int col = (np * 2 + n) * 1024 + base + cit;
    const short* wp = Wt + (size_t)col * KW;
    #pragma unroll
    for (int j = 0; j < 8; ++j)
      vfr[n][j] = *(const bf16x8*)(wp + 512 + kq * 256 + j * 32 + l16 * 8);
    #pragma unroll
    for (int j = 0; j < 4; ++j)
      ufr[n][j] = *(const bf16x8*)(wp + kq * 128 + j * 32 + l16 * 8);
  }

  const float* bias0 = (np == 0) ? b0g : b2g;
  const float* bias1 = (np == 0) ? b1g : b3g;
  const float bv0 = (kq == 0) ? bias0[base + cit] : 0.0f;
  const float bv1 = (kq == 0) ? bias1[base + cit] : 0.0f;

  const int crow = tid >> 4;                // combine row (tid<256)
  const int ccj  = tid & 15;

  // x-staging geometry (two 16B fragments per thread)
  const int xr0_row = tid >> 6;
  const int xr1_row = 8 + (tid >> 6);
  const int x_k0 = (tid & 63) * 8;
  const int x_unit = x_k0 >> 5;
  const int xr0_addr = FR_ADDR(x_unit, (xr0_row << 2) | (tid & 3));
  const int xr1_addr = FR_ADDR(x_unit, (xr1_row << 2) | (tid & 3));
  const short* xsrc0 = xb + (size_t)(b0 + xr0_row) * T_ * I_ + x_k0;
  const short* xsrc1 = xb + (size_t)(b0 + xr1_row) * T_ * I_ + x_k0;

  float c_state = 0.0f;

  // ---- prologue: stage x(0), xu(0), prefetch x(1) ----
  *(int4*)(sx + xr0_addr) = *(const int4*)(xsrc0);
  *(int4*)(sx + xr1_addr) = *(const int4*)(xsrc1);
  __syncthreads();
  f32x4 xacc0 = (f32x4){bv0, bv0, bv0, bv0};
  f32x4 xacc1 = (f32x4){bv1, bv1, bv1, bv1};
  #pragma unroll
  for (int j = 0; j < 4; ++j) {
    const bf16x8 xf = *(const bf16x8*)(sx + FR_ADDR(kq * 4 + j, slot_r));
    xacc0 = __builtin_amdgcn_mfma_f32_16x16x32_bf16(xf, ufr[0][j], xacc0, 0, 0, 0);
    xacc1 = __builtin_amdgcn_mfma_f32_16x16x32_bf16(xf, ufr[1][j], xacc1, 0, 0, 0);
  }
  int4 xr0 = *(const int4*)(xsrc0 + (size_t)1 * I_);
  int4 xr1 = *(const int4*)(xsrc1 + (size_t)1 * I_);

  for (int t = 0; t < T_; ++t) {
    { // ---- A: retry-load h(t) until step-tag bits match, then stage to sh ----
      const unsigned expw = ((t >> 1) & 1) ? 0x00010001u : 0u;
      const short* hsrc = hb + ((size_t)(t & 1) * GROUPS + g) * (MBR * H_);
      int4 v0, v1, v2, v3;
      // calibrated pre-sleep: let the producers' tagged stores reach L3 before
      // the first sample, converting the common {fail, full retry} into {hit}.
      if (t) asm volatile("s_sleep 2" ::: "memory");
      for (;;) {
        #define LDC(ii, vv) { \
          const short* p = hsrc + (size_t)((((ii) * 512 + tid) >> 7)) * H_ \
                           + ((((ii) * 512 + tid) & 127) * 8); \
          asm volatile("global_load_dwordx4 %0, %1, off sc0 sc1" : "=&v"(vv) : "v"(p)); }
        LDC(0, v0) LDC(1, v1) LDC(2, v2) LDC(3, v3)
        #undef LDC
        asm volatile("s_waitcnt vmcnt(0)" ::: "memory");
        __builtin_amdgcn_sched_barrier(0);
        #define XR(vv) (((unsigned)(vv).x ^ expw) | ((unsigned)(vv).y ^ expw) | \
                        ((unsigned)(vv).z ^ expw) | ((unsigned)(vv).w ^ expw))
        const unsigned diff = (XR(v0) | XR(v1) | XR(v2) | XR(v3)) & 0x00010001u;
        #undef XR
        if (__all(diff == 0u)) break;
        asm volatile("s_sleep 1" ::: "memory");
      }
      #define STC(ii, vv) { const int f = (ii) * 512 + tid; const int row = f >> 7; \
        const int k0s = (f & 127) * 8; \
        *(int4*)(sh + FR_ADDR(k0s >> 5, (row << 2) | ((k0s >> 3) & 3))) = vv; }
      STC(0, v0) STC(1, v1) STC(2, v2) STC(3, v3)
      #undef STC
    }
    __syncthreads();                                   // barrier 1

    // ---- B: partial gates = xu_part + h @ V_part (V from registers) ----
    f32x4 acc0 = xacc0, acc1 = xacc1;
    #pragma unroll
    for (int j = 0; j < 8; ++j) {
      const bf16x8 af = *(const bf16x8*)(sh + FR_ADDR(kq * 8 + j, slot_r));
      acc0 = __builtin_amdgcn_mfma_f32_16x16x32_bf16(af, vfr[0][j], acc0, 0, 0, 0);
      acc1 = __builtin_amdgcn_mfma_f32_16x16x32_bf16(af, vfr[1][j], acc1, 0, 0, 0);
    }

    // ---- C: 4-way partial exchange ----
    #pragma unroll
    for (int i = 0; i < 4; ++i) {
      gl[(l16 * 4 + i) * 260 + kq * 64 + (np * 2 + 0) * 16 + cit] = acc0[i];
      gl[(l16 * 4 + i) * 260 + kq * 64 + (np * 2 + 1) * 16 + cit] = acc1[i];
    }
    __syncthreads();                                   // barrier 2

    // ---- D: combine; fire-and-forget tagged h stores; out stores ----
    if (tid < 256) {
      const float* gr = gl + crow * 260;
      float s[4];
      #pragma unroll
      for (int gate = 0; gate < 4; ++gate)
        s[gate] = gr[0 * 64 + gate * 16 + ccj] + gr[1 * 64 + gate * 16 + ccj]
                + gr[2 * 64 + gate * 16 + ccj] + gr[3 * 64 + gate * 16 + ccj];
      const float i_ = sigm(s[0]), f_ = sigm(s[1]), g_ = sigm(s[2]), o_ = sigm(s[3]);
      c_state = f_ * c_state + i_ * g_;
      const float hval = o_ * fast_tanh(c_state);
      if (t + 1 < T_) {
        unsigned hv = (unsigned)f2bf(hval);
        hv = (hv & ~1u) | (unsigned)(((t + 1) >> 1) & 1);   // steal LSB as step tag
        short* hdst = hb + ((size_t)((t + 1) & 1) * GROUPS + g) * (MBR * H_)
                      + (size_t)crow * H_ + base + ccj;
        asm volatile("global_store_short %0, %1, off sc0 sc1" :: "v"(hdst), "v"(hv) : "memory");
      }
      out[((size_t)(b0 + crow) << 19) + (size_t)t * H_ + base + ccj] = hval;
      if (t == T_ - 1) {
        out[(size_t)B_ * T_ * H_ + (size_t)(b0 + crow) * H_ + base + ccj] = hval;
        out[(size_t)B_ * T_ * H_ + (size_t)B_ * H_ + (size_t)(b0 + crow) * H_ + base + ccj] = c_state;
      }
    }

    if (t + 1 < T_) {
      // ---- E: write prefetched x(t+1), prefetch x(t+2) ----
      *(int4*)(sx + xr0_addr) = xr0;
      *(int4*)(sx + xr1_addr) = xr1;
      {
        const size_t tn = (size_t)((t + 2 < T_) ? t + 2 : T_ - 1);
        xr0 = *(const int4*)(xsrc0 + tn * I_);
        xr1 = *(const int4*)(xsrc1 + tn * I_);
      }
      __syncthreads();                                 // barrier 3

      // ---- F: xu(t+1) partial = bias + x(t+1) @ U_part ----
      xacc0 = (f32x4){bv0, bv0, bv0, bv0};
      xacc1 = (f32x4){bv1, bv1, bv1, bv1};
      #pragma unroll
      for (int j = 0; j < 4; ++j) {
        const bf16x8 xf = *(const bf16x8*)(sx + FR_ADDR(kq * 4 + j, slot_r));
        xacc0 = __builtin_amdgcn_mfma_f32_16x16x32_bf16(xf, ufr[0][j], xacc0, 0, 0, 0);
        xacc1 = __builtin_amdgcn_mfma_f32_16x16x32_bf16(xf, ufr[1][j], xacc1, 0, 0, 0);
      }
    }
  }
}

extern "C" void kernel_launch(void* const* d_in, const int* in_sizes, int n_in,
                              void* d_out, int out_size, void* d_ws, size_t ws_size,
                              hipStream_t stream)
{
  const float* x  = (const float*)d_in[0];
  const float* U0 = (const float*)d_in[1];
  const float* Vg0 = (const float*)d_in[2];
  const float* bg0 = (const float*)d_in[3];
  const float* U1 = (const float*)d_in[4];
  const float* Vg1 = (const float*)d_in[5];
  const float* bg1 = (const float*)d_in[6];
  const float* U2 = (const float*)d_in[7];
  const float* Vg2 = (const float*)d_in[8];
  const float* bg2 = (const float*)d_in[9];
  const float* U3 = (const float*)d_in[10];
  const float* Vg3 = (const float*)d_in[11];
  const float* bg3 = (const float*)d_in[12];

  if (ws_size < WS_NEED) return;  // diagnostic: leaves d_out poisoned

  char* ws = (char*)d_ws;
  short* Wt = (short*)(ws + OFF_WT);
  short* xb = (short*)(ws + OFF_XB);
  short* hb = (short*)(ws + OFF_HB);

  (void)hipFuncSetAttribute((const void*)lstm_rec,
                      hipFuncAttributeMaxDynamicSharedMemorySize, LDS_BYTES);

  // par 0: zeros -> valid h(0)=0 with tag bit 0. par 1: 0x0101 -> stale (bit 1) until h(1) lands.
  (void)hipMemsetAsync(ws + OFF_HB, 0x00, 131072, stream);
  (void)hipMemsetAsync(ws + OFF_HB + 131072, 0x01, 131072, stream);
  pack_w_kernel<<<dim3(64, 24), 256, 0, stream>>>(U0, U1, U2, U3, Vg0, Vg1, Vg2, Vg3, Wt);
  xcvt<<<dim3(2048), 256, 0, stream>>>(x, xb);
  lstm_rec<<<dim3(GROUPS * GBLK), 512, LDS_BYTES, stream>>>(
      Wt, xb, bg0, bg1, bg2, bg3, hb, (float*)d_out);
}

// Round 17
// 1122.086 us; speedup vs baseline: 1.0268x; 1.0268x over previous
//
#include <hip/hip_runtime.h>
#include <stdint.h>

#define B_  64
#define T_  512
#define I_  512
#define H_  1024
#define G4  4096
#define KW  1536   // rows of W_t = I_ + H_

#define GROUPS 4
#define GBLK   64    // col-blocks per group
#define MBR    16    // batch rows per group

#define LDS_BYTES 66048

typedef __attribute__((ext_vector_type(8))) short bf16x8;
typedef __attribute__((ext_vector_type(4))) float f32x4;

// ---- ws layout (bytes) ----
#define OFF_WT   ((size_t)0)                        // 4096*1536*2 = 12,582,912
#define OFF_XB   ((size_t)(16u << 20))              // x bf16: 64*512*512*2 = 33,554,432
#define OFF_HB   (OFF_XB + (size_t)33554432)        // tagged h: 2 par * 4 grp * 16 * 1024 * 2B = 262,144
#define WS_NEED  (OFF_HB + (size_t)262144)

__device__ __forceinline__ unsigned short f2bf(float x) {
  unsigned u = __float_as_uint(x);
  u += 0x7FFFu + ((u >> 16) & 1u);        // RNE
  return (unsigned short)(u >> 16);
}
__device__ __forceinline__ float sigm(float x) {
  return 1.0f / (1.0f + __expf(-x));
}
__device__ __forceinline__ float fast_tanh(float x) {
  const float e2 = __expf(2.0f * x);
  return 1.0f - 2.0f / (e2 + 1.0f);
}

// ============ kernel 0: pack [U;V] -> W_t[col][k] bf16 (transposed) ============
__global__ __launch_bounds__(256) void pack_w_kernel(
    const float* __restrict__ U0, const float* __restrict__ U1,
    const float* __restrict__ U2, const float* __restrict__ U3,
    const float* __restrict__ V0, const float* __restrict__ V1,
    const float* __restrict__ V2, const float* __restrict__ V3,
    short* __restrict__ Wt)
{
  __shared__ short sl[64][65];
  const int c0 = blockIdx.x * 64;
  const int k0 = blockIdx.y * 64;
  const int g  = c0 >> 10;
  const int h0 = c0 & 1023;
  const float* srcU = (g == 0 ? U0 : g == 1 ? U1 : g == 2 ? U2 : U3);
  const float* srcV = (g == 0 ? V0 : g == 1 ? V1 : g == 2 ? V2 : V3);
  const float* src  = (k0 < 512) ? (srcU + (size_t)k0 * H_)
                                 : (srcV + (size_t)(k0 - 512) * H_);
  const int tid = threadIdx.x;
  const int cl = tid & 63;
  const int r4 = tid >> 6;
  #pragma unroll
  for (int r = 0; r < 16; ++r) {
    const int kl = r * 4 + r4;
    sl[kl][cl] = (short)f2bf(src[(size_t)kl * H_ + h0 + cl]);
  }
  __syncthreads();
  #pragma unroll
  for (int r = 0; r < 16; ++r) {
    const int cl2 = r * 4 + r4;
    Wt[(size_t)(c0 + cl2) * KW + k0 + cl] = sl[cl][cl2];
  }
}

// ============ kernel 1: x fp32 -> bf16 ============
__global__ __launch_bounds__(256) void xcvt(
    const float* __restrict__ x, short* __restrict__ xb)
{
  const int nt = 524288;
  const int idx = blockIdx.x * 256 + threadIdx.x;
  #pragma unroll
  for (int i = 0; i < 8; ++i) {
    const int j = idx + i * nt;
    const float4 v = ((const float4*)x)[j];
    uint2 pk;
    pk.x = (unsigned)f2bf(v.x) | ((unsigned)f2bf(v.y) << 16);
    pk.y = (unsigned)f2bf(v.z) | ((unsigned)f2bf(v.w) << 16);
    ((uint2*)xb)[j] = pk;
  }
}

// fragment address (shorts): slot XOR-swizzled within unit
#define FR_ADDR(unit, slot) ((((unit) * 64) + ((slot) ^ ((unit) & 7))) * 8)

// ============ kernel 2: persistent recurrence; V in regs; tag-in-data sync ============
__global__ __launch_bounds__(512, 2) void lstm_rec(
    const short* __restrict__ Wt, const short* __restrict__ xb,
    const float* __restrict__ b0g, const float* __restrict__ b1g,
    const float* __restrict__ b2g, const float* __restrict__ b3g,
    short* __restrict__ hb, float* __restrict__ out)
{
  extern __shared__ char smem[];
  short* sh = (short*)smem;                 // 32 KiB h frags (32 units x 64 slots x 16B)
  short* sx = (short*)(smem + 32768);       // 16 KiB x frags (16 units)
  float* gl = (float*)(smem + 49152);       // [16 rows][260] f32 partial-gate exchange

  const int tid = threadIdx.x;
  const int blk = blockIdx.x;
  const int g   = blk >> 6;                 // group (16 batch rows)
  const int bi  = blk & 63;
  const int base = bi * 16;                 // 16 h-cols per block per gate
  const int b0  = g * MBR;

  const int w = tid >> 6, l = tid & 63;
  const int kq = w & 3;                     // K quarter (256 of V-K, 128 of x-K)
  const int np = w >> 2;                    // col half: gates {2np, 2np+1}
  const int cit = l & 15;
  const int l16 = l >> 4;
  const int slot_r = (cit << 2) | l16;

  // ---- one-time: V fragments -> 64 VGPRs, U fragments -> 32 VGPRs ----
  bf16x8 vfr[2][8];
  bf16x8 ufr[2][4];
  #pragma unroll
  for (int n = 0; n < 2; ++n) {
    const int col = (np * 2 + n) * 1024 + base + cit;
    const short* wp = Wt + (size_t)col * KW;
    #pragma unroll
    for (int j = 0; j < 8; ++j)
      vfr[n][j] = *(const bf16x8*)(wp + 512 + kq * 256 + j * 32 + l16 * 8);
    #pragma unroll
    for (int j = 0; j < 4; ++j)
      ufr[n][j] = *(const bf16x8*)(wp + kq * 128 + j * 32 + l16 * 8);
  }

  const float* bias0 = (np == 0) ? b0g : b2g;
  const float* bias1 = (np == 0) ? b1g : b3g;
  const float bv0 = (kq == 0) ? bias0[base + cit] : 0.0f;
  const float bv1 = (kq == 0) ? bias1[base + cit] : 0.0f;

  const int crow = tid >> 4;                // combine row (tid<256)
  const int ccj  = tid & 15;

  // x-staging geometry (two 16B fragments per thread)
  const int xr0_row = tid >> 6;
  const int xr1_row = 8 + (tid >> 6);
  const int x_k0 = (tid & 63) * 8;
  const int x_unit = x_k0 >> 5;
  const int xr0_addr = FR_ADDR(x_unit, (xr0_row << 2) | (tid & 3));
  const int xr1_addr = FR_ADDR(x_unit, (xr1_row << 2) | (tid & 3));
  const short* xsrc0 = xb + (size_t)(b0 + xr0_row) * T_ * I_ + x_k0;
  const short* xsrc1 = xb + (size_t)(b0 + xr1_row) * T_ * I_ + x_k0;

  float c_state = 0.0f;

  // ---- prologue: stage x(0), xu(0), prefetch x(1) ----
  *(int4*)(sx + xr0_addr) = *(const int4*)(xsrc0);
  *(int4*)(sx + xr1_addr) = *(const int4*)(xsrc1);
  __syncthreads();
  f32x4 xacc0 = (f32x4){bv0, bv0, bv0, bv0};
  f32x4 xacc1 = (f32x4){bv1, bv1, bv1, bv1};
  #pragma unroll
  for (int j = 0; j < 4; ++j) {
    const bf16x8 xf = *(const bf16x8*)(sx + FR_ADDR(kq * 4 + j, slot_r));
    xacc0 = __builtin_amdgcn_mfma_f32_16x16x32_bf16(xf, ufr[0][j], xacc0, 0, 0, 0);
    xacc1 = __builtin_amdgcn_mfma_f32_16x16x32_bf16(xf, ufr[1][j], xacc1, 0, 0, 0);
  }
  int4 xr0 = *(const int4*)(xsrc0 + (size_t)1 * I_);
  int4 xr1 = *(const int4*)(xsrc1 + (size_t)1 * I_);

  for (int t = 0; t < T_; ++t) {
    { // ---- A: retry-load h(t) until step-tag bits match, then stage to sh ----
      const unsigned expw = ((t >> 1) & 1) ? 0x00010001u : 0u;
      const short* hsrc = hb + ((size_t)(t & 1) * GROUPS + g) * (MBR * H_);
      int4 v0, v1, v2, v3;
      for (;;) {
        #define LDC(ii, vv) { \
          const short* p = hsrc + (size_t)((((ii) * 512 + tid) >> 7)) * H_ \
                           + ((((ii) * 512 + tid) & 127) * 8); \
          asm volatile("global_load_dwordx4 %0, %1, off sc0 sc1" : "=&v"(vv) : "v"(p)); }
        LDC(0, v0) LDC(1, v1) LDC(2, v2) LDC(3, v3)
        #undef LDC
        asm volatile("s_waitcnt vmcnt(0)" ::: "memory");
        __builtin_amdgcn_sched_barrier(0);
        #define XR(vv) (((unsigned)(vv).x ^ expw) | ((unsigned)(vv).y ^ expw) | \
                        ((unsigned)(vv).z ^ expw) | ((unsigned)(vv).w ^ expw))
        const unsigned diff = (XR(v0) | XR(v1) | XR(v2) | XR(v3)) & 0x00010001u;
        #undef XR
        if (__all(diff == 0u)) break;
        asm volatile("s_sleep 1" ::: "memory");
      }
      #define STC(ii, vv) { const int f = (ii) * 512 + tid; const int row = f >> 7; \
        const int k0s = (f & 127) * 8; \
        *(int4*)(sh + FR_ADDR(k0s >> 5, (row << 2) | ((k0s >> 3) & 3))) = vv; }
      STC(0, v0) STC(1, v1) STC(2, v2) STC(3, v3)
      #undef STC
    }
    __syncthreads();                                   // barrier 1

    // ---- B: partial gates = xu_part + h @ V_part (V from registers) ----
    f32x4 acc0 = xacc0, acc1 = xacc1;
    #pragma unroll
    for (int j = 0; j < 8; ++j) {
      const bf16x8 af = *(const bf16x8*)(sh + FR_ADDR(kq * 8 + j, slot_r));
      acc0 = __builtin_amdgcn_mfma_f32_16x16x32_bf16(af, vfr[0][j], acc0, 0, 0, 0);
      acc1 = __builtin_amdgcn_mfma_f32_16x16x32_bf16(af, vfr[1][j], acc1, 0, 0, 0);
    }

    // ---- C: 4-way partial exchange ----
    #pragma unroll
    for (int i = 0; i < 4; ++i) {
      gl[(l16 * 4 + i) * 260 + kq * 64 + (np * 2 + 0) * 16 + cit] = acc0[i];
      gl[(l16 * 4 + i) * 260 + kq * 64 + (np * 2 + 1) * 16 + cit] = acc1[i];
    }
    __syncthreads();                                   // barrier 2

    // ---- D: combine; fire-and-forget tagged h stores; out stores ----
    if (tid < 256) {
      const float* gr = gl + crow * 260;
      float s[4];
      #pragma unroll
      for (int gate = 0; gate < 4; ++gate)
        s[gate] = gr[0 * 64 + gate * 16 + ccj] + gr[1 * 64 + gate * 16 + ccj]
                + gr[2 * 64 + gate * 16 + ccj] + gr[3 * 64 + gate * 16 + ccj];
      const float i_ = sigm(s[0]), f_ = sigm(s[1]), g_ = sigm(s[2]), o_ = sigm(s[3]);
      c_state = f_ * c_state + i_ * g_;
      const float hval = o_ * fast_tanh(c_state);
      if (t + 1 < T_) {
        unsigned hv = (unsigned)f2bf(hval);
        hv = (hv & ~1u) | (unsigned)(((t + 1) >> 1) & 1);   // steal LSB as step tag
        short* hdst = hb + ((size_t)((t + 1) & 1) * GROUPS + g) * (MBR * H_)
                      + (size_t)crow * H_ + base + ccj;
        asm volatile("global_store_short %0, %1, off sc0 sc1" :: "v"(hdst), "v"(hv) : "memory");
      }
      out[((size_t)(b0 + crow) << 19) + (size_t)t * H_ + base + ccj] = hval;
      if (t == T_ - 1) {
        out[(size_t)B_ * T_ * H_ + (size_t)(b0 + crow) * H_ + base + ccj] = hval;
        out[(size_t)B_ * T_ * H_ + (size_t)B_ * H_ + (size_t)(b0 + crow) * H_ + base + ccj] = c_state;
      }
    }

    if (t + 1 < T_) {
      // ---- E: write prefetched x(t+1), prefetch x(t+2) ----
      *(int4*)(sx + xr0_addr) = xr0;
      *(int4*)(sx + xr1_addr) = xr1;
      {
        const size_t tn = (size_t)((t + 2 < T_) ? t + 2 : T_ - 1);
        xr0 = *(const int4*)(xsrc0 + tn * I_);
        xr1 = *(const int4*)(xsrc1 + tn * I_);
      }
      __syncthreads();                                 // barrier 3

      // ---- F: xu(t+1) partial = bias + x(t+1) @ U_part ----
      xacc0 = (f32x4){bv0, bv0, bv0, bv0};
      xacc1 = (f32x4){bv1, bv1, bv1, bv1};
      #pragma unroll
      for (int j = 0; j < 4; ++j) {
        const bf16x8 xf = *(const bf16x8*)(sx + FR_ADDR(kq * 4 + j, slot_r));
        xacc0 = __builtin_amdgcn_mfma_f32_16x16x32_bf16(xf, ufr[0][j], xacc0, 0, 0, 0);
        xacc1 = __builtin_amdgcn_mfma_f32_16x16x32_bf16(xf, ufr[1][j], xacc1, 0, 0, 0);
      }
    }
  }
}

extern "C" void kernel_launch(void* const* d_in, const int* in_sizes, int n_in,
                              void* d_out, int out_size, void* d_ws, size_t ws_size,
                              hipStream_t stream)
{
  const float* x  = (const float*)d_in[0];
  const float* U0 = (const float*)d_in[1];
  const float* Vg0 = (const float*)d_in[2];
  const float* bg0 = (const float*)d_in[3];
  const float* U1 = (const float*)d_in[4];
  const float* Vg1 = (const float*)d_in[5];
  const float* bg1 = (const float*)d_in[6];
  const float* U2 = (const float*)d_in[7];
  const float* Vg2 = (const float*)d_in[8];
  const float* bg2 = (const float*)d_in[9];
  const float* U3 = (const float*)d_in[10];
  const float* Vg3 = (const float*)d_in[11];
  const float* bg3 = (const float*)d_in[12];

  if (ws_size < WS_NEED) return;  // diagnostic: leaves d_out poisoned

  char* ws = (char*)d_ws;
  short* Wt = (short*)(ws + OFF_WT);
  short* xb = (short*)(ws + OFF_XB);
  short* hb = (short*)(ws + OFF_HB);

  (void)hipFuncSetAttribute((const void*)lstm_rec,
                      hipFuncAttributeMaxDynamicSharedMemorySize, LDS_BYTES);

  // par 0: zeros -> valid h(0)=0 with tag bit 0. par 1: 0x0101 -> stale (bit 1) until h(1) lands.
  (void)hipMemsetAsync(ws + OFF_HB, 0x00, 131072, stream);
  (void)hipMemsetAsync(ws + OFF_HB + 131072, 0x01, 131072, stream);
  pack_w_kernel<<<dim3(64, 24), 256, 0, stream>>>(U0, U1, U2, U3, Vg0, Vg1, Vg2, Vg3, Wt);
  xcvt<<<dim3(2048), 256, 0, stream>>>(x, xb);
  lstm_rec<<<dim3(GROUPS * GBLK), 512, LDS_BYTES, stream>>>(
      Wt, xb, bg0, bg1, bg2, bg3, hb, (float*)d_out);
}